// Round 12
// baseline (36.682 us; speedup 1.0000x reference)
//
#include <hip/hip_runtime.h>
#include <math.h>

// Problem geometry (fixed by the reference setup)
#define CH       48
#define DIM      64
#define SPATIAL  (DIM * DIM * DIM)   // 262144 per (b, c)
#define NB       2
#define VOL      (NB * SPATIAL)      // 524288 per scale volume
#define NS       3
#define CSTRIDE  (DIM * 1024)        // channel stride in f4 (65536)

typedef float f4 __attribute__((ext_vector_type(4)));

// -------------------------------------------------------------------------
// A: channel mix + W box-sum + H box-sum for ONE full (b,d) plane per block.
// 128 blocks x 256 threads.  Plane-complete: H-pool needs no cross-block
// halo and no redundant x reads.  x read exactly once (100.7 MB, nt).
// Output zWH[s][b*64+d][h*16+w4] is LINEAR (no transpose, coalesced stores).
// Thread (w4 = tid&15, r0 = tid>>4) owns rows {r0, r0+16, r0+32, r0+48}.
// -------------------------------------------------------------------------
__global__ __launch_bounds__(256) void kA(
        const float* __restrict__ x,
        const float* __restrict__ fw,
        float* __restrict__ z) {
    __shared__ float sw[NS * CH];
    __shared__ f4 tile[NS][DIM][16];         // 48 KB
    const int tid = threadIdx.x;
    if (tid < NS * CH) sw[tid] = fw[tid];
    __syncthreads();

    const int bd = blockIdx.x;               // b*64 + d
    const int b  = bd >> 6;
    const int w4 = tid & 15;
    const int r0 = tid >> 4;                 // 0..15

    // x f4-index: ((b*CH + c)*DIM + d)*1024 + h*16 + w4
    const f4* xp = (const f4*)x
        + ((size_t)b * CH * DIM + (bd & 63)) * 1024 + r0 * 16 + w4;

    f4 acc[NS][4];
    #pragma unroll
    for (int s = 0; s < NS; ++s)
        #pragma unroll
        for (int rp = 0; rp < 4; ++rp) acc[s][rp] = (f4){0,0,0,0};

    #pragma unroll 4
    for (int c = 0; c < CH; ++c) {
        const f4* cp = xp + (size_t)c * CSTRIDE;
        f4 v0 = __builtin_nontemporal_load(cp);        // row r0
        f4 v1 = __builtin_nontemporal_load(cp + 256);  // row r0+16
        f4 v2 = __builtin_nontemporal_load(cp + 512);  // row r0+32
        f4 v3 = __builtin_nontemporal_load(cp + 768);  // row r0+48
        float s0 = sw[c], s1 = sw[CH + c], s2 = sw[2 * CH + c];
        acc[0][0] += s0 * v0; acc[0][1] += s0 * v1; acc[0][2] += s0 * v2; acc[0][3] += s0 * v3;
        acc[1][0] += s1 * v0; acc[1][1] += s1 * v1; acc[1][2] += s1 * v2; acc[1][3] += s1 * v3;
        acc[2][0] += s2 * v0; acc[2][1] += s2 * v1; acc[2][2] += s2 * v2; acc[2][3] += s2 * v3;
    }

    // channel-mixed plane -> LDS
    #pragma unroll
    for (int s = 0; s < NS; ++s)
        #pragma unroll
        for (int rp = 0; rp < 4; ++rp)
            tile[s][r0 + 16 * rp][w4] = acc[s][rp];
    __syncthreads();

    // W box-sum (within row; zero past row ends == reference zero padding).
    const f4 zero = {0,0,0,0};
    #pragma unroll
    for (int s = 0; s < NS; ++s) {
        const int p = s + 1;
        #pragma unroll
        for (int rp = 0; rp < 4; ++rp) {
            const int r = r0 + 16 * rp;
            f4 m1 = (w4 > 0)  ? tile[s][r][w4 - 1] : zero;
            f4 m0 = acc[s][rp];
            f4 p1 = (w4 < 15) ? tile[s][r][w4 + 1] : zero;
            float f[12] = {m1.x, m1.y, m1.z, m1.w,
                           m0.x, m0.y, m0.z, m0.w,
                           p1.x, p1.y, p1.z, p1.w};
            f4 r4;
            #pragma unroll
            for (int j = 0; j < 4; ++j) {
                float a = 0.f;
                #pragma unroll
                for (int i = -3; i <= 3; ++i)
                    if (i >= -p && i <= p) a += f[4 + j + i];
                r4[j] = a;
            }
            acc[s][rp] = r4;                 // W-pooled, in regs
        }
    }
    __syncthreads();                         // all W reads done

    // write W-pooled back to LDS
    #pragma unroll
    for (int s = 0; s < NS; ++s)
        #pragma unroll
        for (int rp = 0; rp < 4; ++rp)
            tile[s][r0 + 16 * rp][w4] = acc[s][rp];
    __syncthreads();

    // H box-sum (across rows; rows outside [0,63] contribute 0) -> global,
    // LINEAR layout z[s][bd][h*16+w4].
    f4* zp = (f4*)z + (size_t)bd * 1024 + w4;
    #pragma unroll
    for (int s = 0; s < NS; ++s) {
        const int p = s + 1;
        #pragma unroll
        for (int rp = 0; rp < 4; ++rp) {
            const int r = r0 + 16 * rp;
            f4 a = {0,0,0,0};
            #pragma unroll
            for (int i = -3; i <= 3; ++i) {
                const int rr = r + i;
                if (i >= -p && i <= p && rr >= 0 && rr < DIM)
                    a += tile[s][rr][w4];
            }
            zp[(size_t)s * (NB * DIM * 1024) + r * 16] = a;
        }
    }
}

// -------------------------------------------------------------------------
// B: D box-sum + 1/k^3 + cross-scale sum + bias + sigmoid.  Pure streaming:
// 15 coalesced f4 loads per thread from the 6.3 MB L2/L3-resident zWH,
// one nt store.  512 blocks x 256 threads = one thread per output f4.
// -------------------------------------------------------------------------
__global__ __launch_bounds__(256) void kB(
        const float* __restrict__ z,
        const float* __restrict__ fb,
        float* __restrict__ out) {
    const int gid = blockIdx.x * 256 + threadIdx.x;   // 0 .. VOL/4-1
    const int pl  = gid & 1023;              // h*16 + w4 within plane
    const int d   = (gid >> 10) & 63;
    const int b   = gid >> 16;

    const f4* z4 = (const f4*)z;
    const float inv[NS] = {1.f / 27.f, 1.f / 125.f, 1.f / 343.f};
    const float bias = fb[0];
    f4 a2 = {bias, bias, bias, bias};
    #pragma unroll
    for (int s = 0; s < NS; ++s) {
        const int p = s + 1;
        const size_t base = ((size_t)s * NB * DIM + b * DIM) * 1024 + pl;
        f4 a = {0,0,0,0};
        #pragma unroll
        for (int i = -3; i <= 3; ++i) {
            const int dd = d + i;
            if (i >= -p && i <= p && dd >= 0 && dd < DIM)
                a += z4[base + (size_t)dd * 1024];
        }
        a2 += a * inv[s];
    }
    f4 r;
    #pragma unroll
    for (int j = 0; j < 4; ++j) r[j] = 1.f / (1.f + __expf(-a2[j]));
    __builtin_nontemporal_store(r, &((f4*)out)[gid]);
}

// -------------------------------------------------------------------------
extern "C" void kernel_launch(void* const* d_in, const int* in_sizes, int n_in,
                              void* d_out, int out_size, void* d_ws, size_t ws_size,
                              hipStream_t stream) {
    const float* x  = (const float*)d_in[0];   // (2, 48, 64, 64, 64) f32
    const float* fw = (const float*)d_in[1];   // (1, 144) f32
    const float* fb = (const float*)d_in[2];   // (1,) f32
    float* out = (float*)d_out;                // (2, 1, 64, 64, 64) f32

    float* z = (float*)d_ws;                   // 3*VOL floats = 6.29 MB

    // A: channel mix + W-pool + H-pool, one (b,d) plane per block
    kA<<<NB * DIM, 256, 0, stream>>>(x, fw, z);
    // B: D-pool + scale + bias + sigmoid
    kB<<<(VOL / 4) / 256, 256, 0, stream>>>(z, fb, out);
}